// Round 7
// baseline (433.713 us; speedup 1.0000x reference)
//
#include <hip/hip_runtime.h>
#include <hip/hip_fp16.h>

#define N_NODES 50000
#define N_EDGES 800000
#define NB_SCAN 49          // ceil(50000 / 1024)
#define DEG_PAD (NB_SCAN * 1024)   // 50176, zero-padded so int4 loads are unguarded

static __device__ __forceinline__ float lrelu(float x) { return fmaxf(x, 0.2f * x); }

// ---------------- CSR build ----------------
__global__ void k_count(const int* __restrict__ dst, int* __restrict__ deg) {
    int e = blockIdx.x * blockDim.x + threadIdx.x;
    if (e < N_EDGES) atomicAdd(&deg[dst[e]], 1);
}

// Phase A: per-block (1024 elems) sums
__global__ void __launch_bounds__(256) k_scanA(const int* __restrict__ deg,
                                               int* __restrict__ bsum) {
    const int t = threadIdx.x;
    const int b = blockIdx.x;
    const int base = (b * 256 + t) * 4;
    const int4 v = *reinterpret_cast<const int4*>(deg + base);  // padded: safe
    int s = v.x + v.y + v.z + v.w;
#pragma unroll
    for (int off = 32; off > 0; off >>= 1) s += __shfl_down(s, off);
    __shared__ int ws[4];
    if ((t & 63) == 0) ws[t >> 6] = s;
    __syncthreads();
    if (t == 0) bsum[b] = ws[0] + ws[1] + ws[2] + ws[3];
}

// Phase B: exclusive scan of 49 block sums (single wave)
__global__ void __launch_bounds__(64) k_scanB(const int* __restrict__ bsum,
                                              int* __restrict__ boff,
                                              int* __restrict__ rowp) {
    const int t = threadIdx.x;
    const int v = (t < NB_SCAN) ? bsum[t] : 0;
    int inc = v;
#pragma unroll
    for (int off = 1; off < 64; off <<= 1) {
        const int u = __shfl_up(inc, off);
        if (t >= off) inc += u;
    }
    if (t < NB_SCAN) boff[t] = inc - v;
    if (t == 0) rowp[N_NODES] = N_EDGES;  // total degree == E (all dst in range)
}

// Phase C: block-local scan + block offset -> rowp
__global__ void __launch_bounds__(256) k_scanC(const int* __restrict__ deg,
                                               const int* __restrict__ boff,
                                               int* __restrict__ rowp) {
    const int t = threadIdx.x;
    const int b = blockIdx.x;
    const int lane = t & 63;
    const int wv = t >> 6;
    const int base = (b * 256 + t) * 4;
    const int4 v = *reinterpret_cast<const int4*>(deg + base);
    const int s = v.x + v.y + v.z + v.w;
    int inc = s;
#pragma unroll
    for (int off = 1; off < 64; off <<= 1) {
        const int u = __shfl_up(inc, off);
        if (lane >= off) inc += u;
    }
    __shared__ int wsum[4];
    if (lane == 63) wsum[wv] = inc;
    __syncthreads();
    int add = boff[b];
    for (int w = 0; w < wv; ++w) add += wsum[w];
    const int exc = add + inc - s;  // exclusive prefix at this thread's first elem
    if (base < N_NODES) rowp[base] = exc;
    if (base + 1 < N_NODES) rowp[base + 1] = exc + v.x;
    if (base + 2 < N_NODES) rowp[base + 2] = exc + v.x + v.y;
    if (base + 3 < N_NODES) rowp[base + 3] = exc + v.x + v.y + v.z;
}

// scatter: also records row (dst) per CSR slot for the edge-weight kernel
__global__ void k_scatter(const int* __restrict__ src, const int* __restrict__ dst,
                          const int* __restrict__ rowp, int* __restrict__ fill,
                          int* __restrict__ col, int* __restrict__ row) {
    int e = blockIdx.x * blockDim.x + threadIdx.x;
    if (e < N_EDGES) {
        int d = dst[e];
        int pos = rowp[d] + atomicAdd(&fill[d], 1);
        col[pos] = src[e];
        row[pos] = d;
    }
}

// ---------------- edge weights: w[j] = exp(lrelu(el[col[j]] + er[row[j]])) ----
// One thread per CSR slot; el gathers are L2-resident, er reads dst-sorted.
__global__ void __launch_bounds__(256) k_ew(const int* __restrict__ col,
                                            const int* __restrict__ row,
                                            const float* __restrict__ el,
                                            const float* __restrict__ er,
                                            float4* __restrict__ wcsr) {
    int j = blockIdx.x * blockDim.x + threadIdx.x;
    if (j >= N_EDGES) return;
    const int s = col[j];
    const int d = row[j];
    const float4 e = *reinterpret_cast<const float4*>(el + (size_t)s * 4);
    const float4 r = *reinterpret_cast<const float4*>(er + (size_t)d * 4);
    float4 w;
    w.x = __expf(lrelu(e.x + r.x));
    w.y = __expf(lrelu(e.y + r.y));
    w.z = __expf(lrelu(e.z + r.z));
    w.w = 0.f;
    wcsr[j] = w;
}

// ---------------- feat = x @ W : W in VGPRs, x via wave-uniform loads ---------
// block = 192 threads (3 waves; wave h == head h). GROUPS groups of NPG nodes.
// feat layout: half [N][192]; el/er: float [N][4] (padded for float4 in k_ew).
template <int K, int NPG, int GROUPS>
__global__ void __launch_bounds__(192) k_feat(const float* __restrict__ x,
                                              const float* __restrict__ W,
                                              const float* __restrict__ al,
                                              const float* __restrict__ ar,
                                              __half* __restrict__ feat,
                                              float* __restrict__ el,
                                              float* __restrict__ er) {
    const int c = threadIdx.x;  // output column = h*64+f
    const int h = c >> 6;
    float wreg[K];
#pragma unroll
    for (int k = 0; k < K; ++k) wreg[k] = W[k * 192 + c];
    const float alc = al[c];
    const float arc = ar[c];

    for (int g = 0; g < GROUPS; ++g) {
        const int nbase = (blockIdx.x * GROUPS + g) * NPG;  // grid sized exactly
        float acc[NPG];
#pragma unroll
        for (int i = 0; i < NPG; ++i) acc[i] = 0.f;
#pragma unroll
        for (int i = 0; i < NPG; ++i) {
            const int n = __builtin_amdgcn_readfirstlane(nbase + i);
            const float* __restrict__ xr = x + (size_t)n * K;
#pragma unroll
            for (int k = 0; k < K; ++k) acc[i] += xr[k] * wreg[k];
        }
#pragma unroll
        for (int i = 0; i < NPG; ++i) {
            const float a = acc[i];
            feat[(size_t)(nbase + i) * 192 + c] = __float2half(a);
            float e1 = a * alc, e2 = a * arc;
#pragma unroll
            for (int off = 32; off > 0; off >>= 1) {
                e1 += __shfl_down(e1, off);
                e2 += __shfl_down(e2, off);
            }
            if ((c & 63) == 0) {
                el[(size_t)(nbase + i) * 4 + h] = e1;
                er[(size_t)(nbase + i) * 4 + h] = e2;
            }
        }
    }
}

// ---------------- aggregation: one wave per destination node (F=64) ----------
// Weights precomputed in wcsr; loop is gather + fma only.
__global__ void __launch_bounds__(256) k_agg(const __half* __restrict__ feat,
                                             const float4* __restrict__ wcsr,
                                             const float* __restrict__ bias,
                                             const int* __restrict__ rowp,
                                             const int* __restrict__ col,
                                             float* __restrict__ hout) {
    const int n = (blockIdx.x * blockDim.x + threadIdx.x) >> 6;
    const int lane = threadIdx.x & 63;
    if (n >= N_NODES) return;
    const int jb = rowp[n], je = rowp[n + 1];
    float a0 = 0.f, a1 = 0.f, a2 = 0.f;
    float s0 = 0.f, s1 = 0.f, s2 = 0.f;

    int j = jb;
    for (; j + 1 < je; j += 2) {
        const int sA = __builtin_amdgcn_readfirstlane(col[j]);
        const int sB = __builtin_amdgcn_readfirstlane(col[j + 1]);
        const float4 wA = wcsr[j];       // uniform scalar load, independent of col
        const float4 wB = wcsr[j + 1];
        const __half* pA = feat + (size_t)sA * 192;
        const __half* pB = feat + (size_t)sB * 192;
        const float fA0 = __half2float(pA[lane]);
        const float fA1 = __half2float(pA[64 + lane]);
        const float fA2 = __half2float(pA[128 + lane]);
        const float fB0 = __half2float(pB[lane]);
        const float fB1 = __half2float(pB[64 + lane]);
        const float fB2 = __half2float(pB[128 + lane]);
        a0 += wA.x * fA0 + wB.x * fB0;
        a1 += wA.y * fA1 + wB.y * fB1;
        a2 += wA.z * fA2 + wB.z * fB2;
        s0 += wA.x + wB.x;
        s1 += wA.y + wB.y;
        s2 += wA.z + wB.z;
    }
    if (j < je) {
        const int s = __builtin_amdgcn_readfirstlane(col[j]);
        const float4 w = wcsr[j];
        const __half* p = feat + (size_t)s * 192;
        a0 += w.x * __half2float(p[lane]);
        a1 += w.y * __half2float(p[64 + lane]);
        a2 += w.z * __half2float(p[128 + lane]);
        s0 += w.x; s1 += w.y; s2 += w.z;
    }
    float r = 0.f;
    if (je > jb) r = a0 / s0 + a1 / s1 + a2 / s2;
    r += bias[lane] + bias[64 + lane] + bias[128 + lane];
    hout[(size_t)n * 64 + lane] = r;
}

// ---------------- layer 3: feat3 = h @ W3 (64->6), el3/er3 -------------------
__global__ void __launch_bounds__(256) k_feat3(const float* __restrict__ x,
                                               const float* __restrict__ W3,
                                               const float* __restrict__ al3,
                                               const float* __restrict__ ar3,
                                               float* __restrict__ feat3,
                                               float* __restrict__ el3,
                                               float* __restrict__ er3) {
    __shared__ float Wl[64 * 6];
    __shared__ float xl[32 * 64];
    __shared__ float fl[32 * 8];
    const int t = threadIdx.x;
    const int n0 = blockIdx.x * 32;
    const int nvalid = min(32, N_NODES - n0);
    for (int idx = t; idx < 384; idx += 256) Wl[idx] = W3[idx];
    for (int idx = t; idx < nvalid * 64; idx += 256) xl[idx] = x[(size_t)n0 * 64 + idx];
    __syncthreads();

    const int i = t >> 3;      // node within block
    const int slot = t & 7;    // 0..5 = output col, 6..7 idle
    if (i < nvalid && slot < 6) {
        float acc = 0.f;
#pragma unroll
        for (int k4 = 0; k4 < 16; ++k4) {
            const float4 xv = *reinterpret_cast<const float4*>(&xl[i * 64 + 4 * k4]);
            acc += Wl[(4 * k4 + 0) * 6 + slot] * xv.x;
            acc += Wl[(4 * k4 + 1) * 6 + slot] * xv.y;
            acc += Wl[(4 * k4 + 2) * 6 + slot] * xv.z;
            acc += Wl[(4 * k4 + 3) * 6 + slot] * xv.w;
        }
        fl[i * 8 + slot] = acc;
        feat3[(size_t)(n0 + i) * 8 + slot] = acc;
    }
    __syncthreads();
    if (i < nvalid && slot < 6) {
        if (slot < 3) {
            const int h = slot;
            el3[(size_t)(n0 + i) * 4 + h] =
                fl[i * 8 + 2 * h] * al3[2 * h] + fl[i * 8 + 2 * h + 1] * al3[2 * h + 1];
        } else {
            const int h = slot - 3;
            er3[(size_t)(n0 + i) * 4 + h] =
                fl[i * 8 + 2 * h] * ar3[2 * h] + fl[i * 8 + 2 * h + 1] * ar3[2 * h + 1];
        }
    }
}

// ---------------- layer-3 aggregation: 8 lanes per node, precomputed w -------
__global__ void __launch_bounds__(256) k_agg3(const float* __restrict__ feat3,
                                              const float* __restrict__ wcsr,
                                              const float* __restrict__ b3,
                                              const int* __restrict__ rowp,
                                              const int* __restrict__ col,
                                              float* __restrict__ out) {
    const int t = blockIdx.x * blockDim.x + threadIdx.x;
    const int n = t >> 3;
    const int r = t & 7;       // feature slot (0..5 valid; head = r/2)
    if (n >= N_NODES) return;
    int hh = r >> 1; if (hh > 2) hh = 2;
    const int jb = rowp[n], je = rowp[n + 1];
    float a = 0.f, sw = 0.f;
    for (int j = jb; j < je; ++j) {
        const int s = col[j];
        const float w = wcsr[(size_t)j * 4 + hh];
        const float f = feat3[(size_t)s * 8 + r];
        a += w * f;
        sw += w;
    }
    float v = (je > jb && r < 6) ? (a / sw) : 0.f;
    v += __shfl_down(v, 2, 8);
    v += __shfl_down(v, 4, 8);
    if (r < 2) {
        const float bc = b3[r] + b3[r + 2] + b3[r + 4];
        out[(size_t)n * 2 + r] = v + bc;
    }
}

extern "C" void kernel_launch(void* const* d_in, const int* in_sizes, int n_in,
                              void* d_out, int out_size, void* d_ws, size_t ws_size,
                              hipStream_t stream) {
    const float* feats = (const float*)d_in[0];
    const int* src = (const int*)d_in[1];
    const int* dst = (const int*)d_in[2];
    const float* W1 = (const float*)d_in[3];
    const float* al1 = (const float*)d_in[4];
    const float* ar1 = (const float*)d_in[5];
    const float* b1 = (const float*)d_in[6];
    const float* W2 = (const float*)d_in[7];
    const float* al2 = (const float*)d_in[8];
    const float* ar2 = (const float*)d_in[9];
    const float* b2 = (const float*)d_in[10];
    const float* W3 = (const float*)d_in[11];
    const float* al3 = (const float*)d_in[12];
    const float* ar3 = (const float*)d_in[13];
    const float* b3 = (const float*)d_in[14];
    float* out = (float*)d_out;

    char* ws = (char*)d_ws;
    size_t off = 0;
    auto alloc = [&](size_t bytes) {
        void* p = ws + off;
        off += (bytes + 255) & ~(size_t)255;
        return p;
    };
    __half* featH = (__half*)alloc((size_t)N_NODES * 192 * 2);  // 19.2 MB
    float* hbuf = (float*)alloc((size_t)N_NODES * 64 * 4);      // 12.8 MB
    float* el = (float*)alloc((size_t)N_NODES * 4 * 4);
    float* er = (float*)alloc((size_t)N_NODES * 4 * 4);
    int* deg = (int*)alloc((size_t)DEG_PAD * 4);                // zero-padded to 50176
    int* fill = (int*)alloc((size_t)DEG_PAD * 4);
    int* rowp = (int*)alloc((size_t)(N_NODES + 1) * 4);
    int* col = (int*)alloc((size_t)N_EDGES * 4);
    int* row = (int*)alloc((size_t)N_EDGES * 4);
    float4* wcsr = (float4*)alloc((size_t)N_EDGES * 16);        // 12.8 MB
    int* bsum = (int*)alloc(64 * 4);
    int* boff = (int*)alloc(64 * 4);
    float* feat3 = (float*)alloc((size_t)N_NODES * 8 * 4);
    float* el3 = (float*)alloc((size_t)N_NODES * 4 * 4);
    float* er3 = (float*)alloc((size_t)N_NODES * 4 * 4);
    (void)ws_size;

    // ---- CSR build (deg & fill adjacent -> one memset covers both + pads) ----
    hipMemsetAsync(deg, 0, 2 * (size_t)DEG_PAD * 4, stream);
    int eb = (N_EDGES + 255) / 256;
    k_count<<<eb, 256, 0, stream>>>(dst, deg);
    k_scanA<<<NB_SCAN, 256, 0, stream>>>(deg, bsum);
    k_scanB<<<1, 64, 0, stream>>>(bsum, boff, rowp);
    k_scanC<<<NB_SCAN, 256, 0, stream>>>(deg, boff, rowp);
    k_scatter<<<eb, 256, 0, stream>>>(src, dst, rowp, fill, col, row);

    const int fb = 2500;                    // 2500 blocks x 5 groups x 4 = 50000
    const int ab = (N_NODES + 3) / 4;       // k_agg: 4 waves/block
    const int nb3 = (N_NODES + 31) / 32;    // k_feat3 / k_agg3: 32 nodes/block

    // ---- layer 1 ----
    k_feat<9, 4, 5><<<fb, 192, 0, stream>>>(feats, W1, al1, ar1, featH, el, er);
    k_ew<<<eb, 256, 0, stream>>>(col, row, el, er, wcsr);
    k_agg<<<ab, 256, 0, stream>>>(featH, wcsr, b1, rowp, col, hbuf);

    // ---- layer 2 ----
    k_feat<64, 4, 5><<<fb, 192, 0, stream>>>(hbuf, W2, al2, ar2, featH, el, er);
    k_ew<<<eb, 256, 0, stream>>>(col, row, el, er, wcsr);
    k_agg<<<ab, 256, 0, stream>>>(featH, wcsr, b2, rowp, col, hbuf);

    // ---- layer 3 ----
    k_feat3<<<nb3, 256, 0, stream>>>(hbuf, W3, al3, ar3, feat3, el3, er3);
    k_ew<<<eb, 256, 0, stream>>>(col, row, el3, er3, wcsr);
    k_agg3<<<nb3, 256, 0, stream>>>(feat3, (const float*)wcsr, b3, rowp, col, out);
}

// Round 8
// 409.467 us; speedup vs baseline: 1.0592x; 1.0592x over previous
//
#include <hip/hip_runtime.h>
#include <hip/hip_fp16.h>

#define N_NODES 50000
#define N_EDGES 800000
#define NB_SCAN 49          // ceil(50000 / 1024)
#define DEG_PAD (NB_SCAN * 1024)   // 50176, zero-padded so int4 loads are unguarded

static __device__ __forceinline__ float lrelu(float x) { return fmaxf(x, 0.2f * x); }

// ---------------- CSR build ----------------
__global__ void k_count(const int* __restrict__ dst, int* __restrict__ deg) {
    int e = blockIdx.x * blockDim.x + threadIdx.x;
    if (e < N_EDGES) atomicAdd(&deg[dst[e]], 1);
}

__global__ void __launch_bounds__(256) k_scanA(const int* __restrict__ deg,
                                               int* __restrict__ bsum) {
    const int t = threadIdx.x;
    const int b = blockIdx.x;
    const int base = (b * 256 + t) * 4;
    const int4 v = *reinterpret_cast<const int4*>(deg + base);  // padded: safe
    int s = v.x + v.y + v.z + v.w;
#pragma unroll
    for (int off = 32; off > 0; off >>= 1) s += __shfl_down(s, off);
    __shared__ int ws[4];
    if ((t & 63) == 0) ws[t >> 6] = s;
    __syncthreads();
    if (t == 0) bsum[b] = ws[0] + ws[1] + ws[2] + ws[3];
}

__global__ void __launch_bounds__(64) k_scanB(const int* __restrict__ bsum,
                                              int* __restrict__ boff,
                                              int* __restrict__ rowp) {
    const int t = threadIdx.x;
    const int v = (t < NB_SCAN) ? bsum[t] : 0;
    int inc = v;
#pragma unroll
    for (int off = 1; off < 64; off <<= 1) {
        const int u = __shfl_up(inc, off);
        if (t >= off) inc += u;
    }
    if (t < NB_SCAN) boff[t] = inc - v;
    if (t == 0) rowp[N_NODES] = N_EDGES;
}

__global__ void __launch_bounds__(256) k_scanC(const int* __restrict__ deg,
                                               const int* __restrict__ boff,
                                               int* __restrict__ rowp) {
    const int t = threadIdx.x;
    const int b = blockIdx.x;
    const int lane = t & 63;
    const int wv = t >> 6;
    const int base = (b * 256 + t) * 4;
    const int4 v = *reinterpret_cast<const int4*>(deg + base);
    const int s = v.x + v.y + v.z + v.w;
    int inc = s;
#pragma unroll
    for (int off = 1; off < 64; off <<= 1) {
        const int u = __shfl_up(inc, off);
        if (lane >= off) inc += u;
    }
    __shared__ int wsum[4];
    if (lane == 63) wsum[wv] = inc;
    __syncthreads();
    int add = boff[b];
    for (int w = 0; w < wv; ++w) add += wsum[w];
    const int exc = add + inc - s;
    if (base < N_NODES) rowp[base] = exc;
    if (base + 1 < N_NODES) rowp[base + 1] = exc + v.x;
    if (base + 2 < N_NODES) rowp[base + 2] = exc + v.x + v.y;
    if (base + 3 < N_NODES) rowp[base + 3] = exc + v.x + v.y + v.z;
}

// scatter: single 8B write per edge {src, dst} -> crs[pos]
__global__ void k_scatter(const int* __restrict__ src, const int* __restrict__ dst,
                          const int* __restrict__ rowp, int* __restrict__ fill,
                          int2* __restrict__ crs) {
    int e = blockIdx.x * blockDim.x + threadIdx.x;
    if (e < N_EDGES) {
        int d = dst[e];
        int pos = rowp[d] + atomicAdd(&fill[d], 1);
        crs[pos] = make_int2(src[e], d);
    }
}

// ---------------- Wa/Wr precompute: Wa[k][h] = sum_f W[k,h*F+f]*al[h,f] ------
template <int K, int F>
__global__ void __launch_bounds__(192) k_prep(const float* __restrict__ W,
                                              const float* __restrict__ al,
                                              const float* __restrict__ ar,
                                              float* __restrict__ Wa,
                                              float* __restrict__ Wr) {
    const int t = threadIdx.x;
    if (t < 3 * K) {
        const int h = t / K, k = t % K;
        float sa = 0.f, sr = 0.f;
        for (int f = 0; f < F; ++f) {
            const float w = W[k * 3 * F + h * F + f];
            sa += w * al[h * F + f];
            sr += w * ar[h * F + f];
        }
        Wa[k * 4 + h] = sa;
        Wr[k * 4 + h] = sr;
        if (h == 0) { Wa[k * 4 + 3] = 0.f; Wr[k * 4 + 3] = 0.f; }
    }
}

// ---------------- el/er = x @ Wa / x @ Wr : thread per node ------------------
template <int K>
__global__ void __launch_bounds__(256) k_el(const float* __restrict__ x,
                                            const float* __restrict__ Wa,
                                            const float* __restrict__ Wr,
                                            float* __restrict__ el,
                                            float* __restrict__ er) {
    __shared__ float sWa[K * 4];
    __shared__ float sWr[K * 4];
    const int t = threadIdx.x;
    for (int i = t; i < K * 4; i += 256) { sWa[i] = Wa[i]; sWr[i] = Wr[i]; }
    __syncthreads();
    const int n = blockIdx.x * 256 + t;
    if (n >= N_NODES) return;
    float a0 = 0.f, a1 = 0.f, a2 = 0.f, r0 = 0.f, r1 = 0.f, r2 = 0.f;
    const float* __restrict__ xr = x + (size_t)n * K;
#pragma unroll 4
    for (int k = 0; k < K; ++k) {
        const float xv = xr[k];
        a0 += xv * sWa[k * 4 + 0];
        a1 += xv * sWa[k * 4 + 1];
        a2 += xv * sWa[k * 4 + 2];
        r0 += xv * sWr[k * 4 + 0];
        r1 += xv * sWr[k * 4 + 1];
        r2 += xv * sWr[k * 4 + 2];
    }
    *reinterpret_cast<float4*>(el + (size_t)n * 4) = make_float4(a0, a1, a2, 0.f);
    *reinterpret_cast<float4*>(er + (size_t)n * 4) = make_float4(r0, r1, r2, 0.f);
}

// ---------------- edge weights: w[j] = exp(lrelu(el[src] + er[dst])) ---------
__global__ void __launch_bounds__(256) k_ew(const int2* __restrict__ crs,
                                            const float* __restrict__ el,
                                            const float* __restrict__ er,
                                            float4* __restrict__ wcsr) {
    int j = blockIdx.x * blockDim.x + threadIdx.x;
    if (j >= N_EDGES) return;
    const int2 sd = crs[j];
    const float4 e = *reinterpret_cast<const float4*>(el + (size_t)sd.x * 4);
    const float4 r = *reinterpret_cast<const float4*>(er + (size_t)sd.y * 4);
    float4 w;
    w.x = __expf(lrelu(e.x + r.x));
    w.y = __expf(lrelu(e.y + r.y));
    w.z = __expf(lrelu(e.z + r.z));
    w.w = 0.f;
    wcsr[j] = w;
}

// ---------------- feat = x @ W : pure GEMM + fp16 store ----------------------
// block = 192 threads. W column in VGPRs; x rows wave-uniform (scalar loads).
template <int K, int NPG, int GROUPS>
__global__ void __launch_bounds__(192) k_feat(const float* __restrict__ x,
                                              const float* __restrict__ W,
                                              __half* __restrict__ feat) {
    const int c = threadIdx.x;  // output column = h*64+f
    float wreg[K];
#pragma unroll
    for (int k = 0; k < K; ++k) wreg[k] = W[k * 192 + c];

    for (int g = 0; g < GROUPS; ++g) {
        const int nbase = (blockIdx.x * GROUPS + g) * NPG;  // grid sized exactly
        float acc[NPG];
#pragma unroll
        for (int i = 0; i < NPG; ++i) acc[i] = 0.f;
#pragma unroll
        for (int i = 0; i < NPG; ++i) {
            const int n = __builtin_amdgcn_readfirstlane(nbase + i);
            const float* __restrict__ xr = x + (size_t)n * K;
#pragma unroll
            for (int k = 0; k < K; ++k) acc[i] += xr[k] * wreg[k];
        }
#pragma unroll
        for (int i = 0; i < NPG; ++i)
            feat[(size_t)(nbase + i) * 192 + c] = __float2half(acc[i]);
    }
}

// ---------------- aggregation: one wave per destination node (F=64) ----------
__global__ void __launch_bounds__(256) k_agg(const __half* __restrict__ feat,
                                             const float4* __restrict__ wcsr,
                                             const float* __restrict__ bias,
                                             const int* __restrict__ rowp,
                                             const int* __restrict__ crsi,
                                             float* __restrict__ hout) {
    const int n = (blockIdx.x * blockDim.x + threadIdx.x) >> 6;
    const int lane = threadIdx.x & 63;
    if (n >= N_NODES) return;
    const int jb = rowp[n], je = rowp[n + 1];
    float a0 = 0.f, a1 = 0.f, a2 = 0.f;
    float s0 = 0.f, s1 = 0.f, s2 = 0.f;

    int j = jb;
    for (; j + 1 < je; j += 2) {
        const int sA = __builtin_amdgcn_readfirstlane(crsi[2 * j]);
        const int sB = __builtin_amdgcn_readfirstlane(crsi[2 * j + 2]);
        const float4 wA = wcsr[j];
        const float4 wB = wcsr[j + 1];
        const __half* pA = feat + (size_t)sA * 192;
        const __half* pB = feat + (size_t)sB * 192;
        const float fA0 = __half2float(pA[lane]);
        const float fA1 = __half2float(pA[64 + lane]);
        const float fA2 = __half2float(pA[128 + lane]);
        const float fB0 = __half2float(pB[lane]);
        const float fB1 = __half2float(pB[64 + lane]);
        const float fB2 = __half2float(pB[128 + lane]);
        a0 += wA.x * fA0 + wB.x * fB0;
        a1 += wA.y * fA1 + wB.y * fB1;
        a2 += wA.z * fA2 + wB.z * fB2;
        s0 += wA.x + wB.x;
        s1 += wA.y + wB.y;
        s2 += wA.z + wB.z;
    }
    if (j < je) {
        const int s = __builtin_amdgcn_readfirstlane(crsi[2 * j]);
        const float4 w = wcsr[j];
        const __half* p = feat + (size_t)s * 192;
        a0 += w.x * __half2float(p[lane]);
        a1 += w.y * __half2float(p[64 + lane]);
        a2 += w.z * __half2float(p[128 + lane]);
        s0 += w.x; s1 += w.y; s2 += w.z;
    }
    float r = 0.f;
    if (je > jb) r = a0 / s0 + a1 / s1 + a2 / s2;
    r += bias[lane] + bias[64 + lane] + bias[128 + lane];
    hout[(size_t)n * 64 + lane] = r;
}

// ---------------- layer 3: feat3 = h @ W3 (64->6) ----------------------------
__global__ void __launch_bounds__(256) k_feat3(const float* __restrict__ x,
                                               const float* __restrict__ W3,
                                               float* __restrict__ feat3) {
    __shared__ float Wl[64 * 6];
    __shared__ float xl[32 * 64];
    const int t = threadIdx.x;
    const int n0 = blockIdx.x * 32;
    const int nvalid = min(32, N_NODES - n0);
    for (int idx = t; idx < 384; idx += 256) Wl[idx] = W3[idx];
    for (int idx = t; idx < nvalid * 64; idx += 256) xl[idx] = x[(size_t)n0 * 64 + idx];
    __syncthreads();

    const int i = t >> 3;      // node within block
    const int slot = t & 7;    // 0..5 = output col, 6..7 idle
    if (i < nvalid && slot < 6) {
        float acc = 0.f;
#pragma unroll
        for (int k4 = 0; k4 < 16; ++k4) {
            const float4 xv = *reinterpret_cast<const float4*>(&xl[i * 64 + 4 * k4]);
            acc += Wl[(4 * k4 + 0) * 6 + slot] * xv.x;
            acc += Wl[(4 * k4 + 1) * 6 + slot] * xv.y;
            acc += Wl[(4 * k4 + 2) * 6 + slot] * xv.z;
            acc += Wl[(4 * k4 + 3) * 6 + slot] * xv.w;
        }
        feat3[(size_t)(n0 + i) * 8 + slot] = acc;
    }
}

// ---------------- layer-3 aggregation: 8 lanes per node, precomputed w -------
__global__ void __launch_bounds__(256) k_agg3(const float* __restrict__ feat3,
                                              const float* __restrict__ wcsr,
                                              const float* __restrict__ b3,
                                              const int* __restrict__ rowp,
                                              const int* __restrict__ crsi,
                                              float* __restrict__ out) {
    const int t = blockIdx.x * blockDim.x + threadIdx.x;
    const int n = t >> 3;
    const int r = t & 7;       // feature slot (0..5 valid; head = r/2)
    if (n >= N_NODES) return;
    int hh = r >> 1; if (hh > 2) hh = 2;
    const int jb = rowp[n], je = rowp[n + 1];
    float a = 0.f, sw = 0.f;
    for (int j = jb; j < je; ++j) {
        const int s = crsi[2 * j];
        const float w = wcsr[(size_t)j * 4 + hh];
        const float f = feat3[(size_t)s * 8 + r];
        a += w * f;
        sw += w;
    }
    float v = (je > jb && r < 6) ? (a / sw) : 0.f;
    v += __shfl_down(v, 2, 8);
    v += __shfl_down(v, 4, 8);
    if (r < 2) {
        const float bc = b3[r] + b3[r + 2] + b3[r + 4];
        out[(size_t)n * 2 + r] = v + bc;
    }
}

extern "C" void kernel_launch(void* const* d_in, const int* in_sizes, int n_in,
                              void* d_out, int out_size, void* d_ws, size_t ws_size,
                              hipStream_t stream) {
    const float* feats = (const float*)d_in[0];
    const int* src = (const int*)d_in[1];
    const int* dst = (const int*)d_in[2];
    const float* W1 = (const float*)d_in[3];
    const float* al1 = (const float*)d_in[4];
    const float* ar1 = (const float*)d_in[5];
    const float* b1 = (const float*)d_in[6];
    const float* W2 = (const float*)d_in[7];
    const float* al2 = (const float*)d_in[8];
    const float* ar2 = (const float*)d_in[9];
    const float* b2 = (const float*)d_in[10];
    const float* W3 = (const float*)d_in[11];
    const float* al3 = (const float*)d_in[12];
    const float* ar3 = (const float*)d_in[13];
    const float* b3 = (const float*)d_in[14];
    float* out = (float*)d_out;

    char* ws = (char*)d_ws;
    size_t off = 0;
    auto alloc = [&](size_t bytes) {
        void* p = ws + off;
        off += (bytes + 255) & ~(size_t)255;
        return p;
    };
    __half* featH = (__half*)alloc((size_t)N_NODES * 192 * 2);  // 19.2 MB
    float* hbuf = (float*)alloc((size_t)N_NODES * 64 * 4);      // 12.8 MB
    float* el = (float*)alloc((size_t)N_NODES * 4 * 4);
    float* er = (float*)alloc((size_t)N_NODES * 4 * 4);
    int* deg = (int*)alloc((size_t)DEG_PAD * 4);                // zero-padded to 50176
    int* fill = (int*)alloc((size_t)DEG_PAD * 4);
    int* rowp = (int*)alloc((size_t)(N_NODES + 1) * 4);
    int2* crs = (int2*)alloc((size_t)N_EDGES * 8);              // {src,dst} per CSR slot
    float4* wcsr = (float4*)alloc((size_t)N_EDGES * 16);        // 12.8 MB
    int* bsum = (int*)alloc(64 * 4);
    int* boff = (int*)alloc(64 * 4);
    float* Wa = (float*)alloc(64 * 4 * 4);
    float* Wr = (float*)alloc(64 * 4 * 4);
    float* feat3 = (float*)alloc((size_t)N_NODES * 8 * 4);
    float* el3 = (float*)alloc((size_t)N_NODES * 4 * 4);
    float* er3 = (float*)alloc((size_t)N_NODES * 4 * 4);
    (void)ws_size;

    // ---- CSR build ----
    hipMemsetAsync(deg, 0, 2 * (size_t)DEG_PAD * 4, stream);
    int eb = (N_EDGES + 255) / 256;
    k_count<<<eb, 256, 0, stream>>>(dst, deg);
    k_scanA<<<NB_SCAN, 256, 0, stream>>>(deg, bsum);
    k_scanB<<<1, 64, 0, stream>>>(bsum, boff, rowp);
    k_scanC<<<NB_SCAN, 256, 0, stream>>>(deg, boff, rowp);
    k_scatter<<<eb, 256, 0, stream>>>(src, dst, rowp, fill, crs);

    const int fb = 2500;                    // 2500 blocks x 5 groups x 4 = 50000
    const int ab = (N_NODES + 3) / 4;       // k_agg: 4 waves/block
    const int nb = (N_NODES + 255) / 256;   // thread-per-node blocks
    const int nb3 = (N_NODES + 31) / 32;    // k_feat3 / k_agg3: 32 nodes/block
    const int* crsi = (const int*)crs;

    // ---- layer 1 ----
    k_prep<9, 64><<<1, 192, 0, stream>>>(W1, al1, ar1, Wa, Wr);
    k_el<9><<<nb, 256, 0, stream>>>(feats, Wa, Wr, el, er);
    k_feat<9, 4, 5><<<fb, 192, 0, stream>>>(feats, W1, featH);
    k_ew<<<eb, 256, 0, stream>>>(crs, el, er, wcsr);
    k_agg<<<ab, 256, 0, stream>>>(featH, wcsr, b1, rowp, crsi, hbuf);

    // ---- layer 2 ----
    k_prep<64, 64><<<1, 192, 0, stream>>>(W2, al2, ar2, Wa, Wr);
    k_el<64><<<nb, 256, 0, stream>>>(hbuf, Wa, Wr, el, er);
    k_feat<64, 4, 5><<<fb, 192, 0, stream>>>(hbuf, W2, featH);
    k_ew<<<eb, 256, 0, stream>>>(crs, el, er, wcsr);
    k_agg<<<ab, 256, 0, stream>>>(featH, wcsr, b2, rowp, crsi, hbuf);

    // ---- layer 3 ----
    k_prep<64, 2><<<1, 192, 0, stream>>>(W3, al3, ar3, Wa, Wr);
    k_el<64><<<nb, 256, 0, stream>>>(hbuf, Wa, Wr, el3, er3);
    k_feat3<<<nb3, 256, 0, stream>>>(hbuf, W3, feat3);
    k_ew<<<eb, 256, 0, stream>>>(crs, el3, er3, wcsr);
    k_agg3<<<nb3, 256, 0, stream>>>(feat3, (const float*)wcsr, b3, rowp, crsi, out);
}

// Round 9
// 405.078 us; speedup vs baseline: 1.0707x; 1.0108x over previous
//
#include <hip/hip_runtime.h>
#include <hip/hip_fp16.h>

#define N_NODES 50000
#define N_EDGES 800000
#define NB_SCAN 49          // ceil(50000 / 1024)
#define DEG_PAD (NB_SCAN * 1024)   // 50176, zero-padded so int4 loads are unguarded

static __device__ __forceinline__ float lrelu(float x) { return fmaxf(x, 0.2f * x); }

// ---------------- CSR build ----------------
__global__ void k_count(const int* __restrict__ dst, int* __restrict__ deg) {
    int e = blockIdx.x * blockDim.x + threadIdx.x;
    if (e < N_EDGES) atomicAdd(&deg[dst[e]], 1);
}

__global__ void __launch_bounds__(256) k_scanA(const int* __restrict__ deg,
                                               int* __restrict__ bsum) {
    const int t = threadIdx.x;
    const int b = blockIdx.x;
    const int base = (b * 256 + t) * 4;
    const int4 v = *reinterpret_cast<const int4*>(deg + base);  // padded: safe
    int s = v.x + v.y + v.z + v.w;
#pragma unroll
    for (int off = 32; off > 0; off >>= 1) s += __shfl_down(s, off);
    __shared__ int ws[4];
    if ((t & 63) == 0) ws[t >> 6] = s;
    __syncthreads();
    if (t == 0) bsum[b] = ws[0] + ws[1] + ws[2] + ws[3];
}

__global__ void __launch_bounds__(64) k_scanB(const int* __restrict__ bsum,
                                              int* __restrict__ boff,
                                              int* __restrict__ rowp) {
    const int t = threadIdx.x;
    const int v = (t < NB_SCAN) ? bsum[t] : 0;
    int inc = v;
#pragma unroll
    for (int off = 1; off < 64; off <<= 1) {
        const int u = __shfl_up(inc, off);
        if (t >= off) inc += u;
    }
    if (t < NB_SCAN) boff[t] = inc - v;
    if (t == 0) rowp[N_NODES] = N_EDGES;
}

__global__ void __launch_bounds__(256) k_scanC(const int* __restrict__ deg,
                                               const int* __restrict__ boff,
                                               int* __restrict__ rowp) {
    const int t = threadIdx.x;
    const int b = blockIdx.x;
    const int lane = t & 63;
    const int wv = t >> 6;
    const int base = (b * 256 + t) * 4;
    const int4 v = *reinterpret_cast<const int4*>(deg + base);
    const int s = v.x + v.y + v.z + v.w;
    int inc = s;
#pragma unroll
    for (int off = 1; off < 64; off <<= 1) {
        const int u = __shfl_up(inc, off);
        if (lane >= off) inc += u;
    }
    __shared__ int wsum[4];
    if (lane == 63) wsum[wv] = inc;
    __syncthreads();
    int add = boff[b];
    for (int w = 0; w < wv; ++w) add += wsum[w];
    const int exc = add + inc - s;
    if (base < N_NODES) rowp[base] = exc;
    if (base + 1 < N_NODES) rowp[base + 1] = exc + v.x;
    if (base + 2 < N_NODES) rowp[base + 2] = exc + v.x + v.y;
    if (base + 3 < N_NODES) rowp[base + 3] = exc + v.x + v.y + v.z;
}

// scatter: single 4B write per edge (src only; dst is implicit via CSR row)
__global__ void k_scatter(const int* __restrict__ src, const int* __restrict__ dst,
                          const int* __restrict__ rowp, int* __restrict__ fill,
                          int* __restrict__ col) {
    int e = blockIdx.x * blockDim.x + threadIdx.x;
    if (e < N_EDGES) {
        int d = dst[e];
        int pos = rowp[d] + atomicAdd(&fill[d], 1);
        col[pos] = src[e];
    }
}

// ---------------- el/er planes: el[h][n] = sum_k x[n,k] * Wa[k][h] -----------
// Wa/Wr built in LDS from W,al,ar (fused prep). Thread per node.
template <int K, int F>
__global__ void __launch_bounds__(256) k_el(const float* __restrict__ x,
                                            const float* __restrict__ W,
                                            const float* __restrict__ al,
                                            const float* __restrict__ ar,
                                            float* __restrict__ el,
                                            float* __restrict__ er) {
    __shared__ float sWa[K * 3];
    __shared__ float sWr[K * 3];
    const int t = threadIdx.x;
    if (t < 3 * K) {
        const int h = t / K, k = t % K;
        float sa = 0.f, sr = 0.f;
        for (int f = 0; f < F; ++f) {
            const float w = W[k * 3 * F + h * F + f];
            sa += w * al[h * F + f];
            sr += w * ar[h * F + f];
        }
        sWa[k * 3 + h] = sa;
        sWr[k * 3 + h] = sr;
    }
    __syncthreads();
    const int n = blockIdx.x * 256 + t;
    if (n >= N_NODES) return;
    const float* __restrict__ xr = x + (size_t)n * K;
    float a0 = 0.f, a1 = 0.f, a2 = 0.f, r0 = 0.f, r1 = 0.f, r2 = 0.f;
#pragma unroll 4
    for (int k = 0; k < K; ++k) {
        const float xv = xr[k];
        a0 += xv * sWa[k * 3 + 0];
        a1 += xv * sWa[k * 3 + 1];
        a2 += xv * sWa[k * 3 + 2];
        r0 += xv * sWr[k * 3 + 0];
        r1 += xv * sWr[k * 3 + 1];
        r2 += xv * sWr[k * 3 + 2];
    }
    el[0 * N_NODES + n] = a0;
    el[1 * N_NODES + n] = a1;
    el[2 * N_NODES + n] = a2;
    er[0 * N_NODES + n] = r0;
    er[1 * N_NODES + n] = r1;
    er[2 * N_NODES + n] = r2;
}

// ---------------- feat = x @ W : pure GEMM, head-major fp16 out --------------
// block = 192 threads. W column in VGPRs; x rows wave-uniform (scalar loads).
// feat layout: half [3][N][64]  (head plane, contiguous 128B per (n,h) row)
template <int K, int NPG, int GROUPS>
__global__ void __launch_bounds__(192) k_feat(const float* __restrict__ x,
                                              const float* __restrict__ W,
                                              __half* __restrict__ feat) {
    const int c = threadIdx.x;  // W column = h*64+f
    const int h = c >> 6;
    const int f = c & 63;
    float wreg[K];
#pragma unroll
    for (int k = 0; k < K; ++k) wreg[k] = W[k * 192 + c];
    __half* __restrict__ fplane = feat + (size_t)h * N_NODES * 64 + f;

    for (int g = 0; g < GROUPS; ++g) {
        const int nbase = (blockIdx.x * GROUPS + g) * NPG;  // grid sized exactly
        float acc[NPG];
#pragma unroll
        for (int i = 0; i < NPG; ++i) acc[i] = 0.f;
#pragma unroll
        for (int i = 0; i < NPG; ++i) {
            const int n = __builtin_amdgcn_readfirstlane(nbase + i);
            const float* __restrict__ xr = x + (size_t)n * K;
#pragma unroll
            for (int k = 0; k < K; ++k) acc[i] += xr[k] * wreg[k];
        }
#pragma unroll
        for (int i = 0; i < NPG; ++i)
            fplane[(size_t)(nbase + i) * 64] = __float2half(acc[i]);
    }
}

// ---------------- aggregation: wave per (node, head); LDS head-combine -------
__global__ void __launch_bounds__(192) k_agg(const __half* __restrict__ feat,
                                             const float* __restrict__ el,
                                             const float* __restrict__ er,
                                             const float* __restrict__ bias,
                                             const int* __restrict__ rowp,
                                             const int* __restrict__ col,
                                             float* __restrict__ hout) {
    const int n = blockIdx.x;
    const int h = threadIdx.x >> 6;
    const int lane = threadIdx.x & 63;
    const int jb = rowp[n], je = rowp[n + 1];
    const float ern = er[(size_t)h * N_NODES + n];
    const float* __restrict__ elh = el + (size_t)h * N_NODES;
    const __half* __restrict__ fh = feat + (size_t)h * N_NODES * 64;

    float a = 0.f, sw = 0.f;
    int j = jb;
    for (; j + 3 < je; j += 4) {
        const int s0 = __builtin_amdgcn_readfirstlane(col[j]);
        const int s1 = __builtin_amdgcn_readfirstlane(col[j + 1]);
        const int s2 = __builtin_amdgcn_readfirstlane(col[j + 2]);
        const int s3 = __builtin_amdgcn_readfirstlane(col[j + 3]);
        const float e0 = elh[s0], e1 = elh[s1], e2 = elh[s2], e3 = elh[s3];
        const float f0 = __half2float(fh[(size_t)s0 * 64 + lane]);
        const float f1 = __half2float(fh[(size_t)s1 * 64 + lane]);
        const float f2 = __half2float(fh[(size_t)s2 * 64 + lane]);
        const float f3 = __half2float(fh[(size_t)s3 * 64 + lane]);
        const float w0 = __expf(lrelu(e0 + ern));
        const float w1 = __expf(lrelu(e1 + ern));
        const float w2 = __expf(lrelu(e2 + ern));
        const float w3 = __expf(lrelu(e3 + ern));
        a += w0 * f0 + w1 * f1 + w2 * f2 + w3 * f3;
        sw += w0 + w1 + w2 + w3;
    }
    for (; j < je; ++j) {
        const int s = __builtin_amdgcn_readfirstlane(col[j]);
        const float w = __expf(lrelu(elh[s] + ern));
        a += w * __half2float(fh[(size_t)s * 64 + lane]);
        sw += w;
    }

    __shared__ float part[192];
    part[threadIdx.x] = (je > jb) ? (a / sw) : 0.f;
    __syncthreads();
    if (threadIdx.x < 64) {
        const float v = part[lane] + part[64 + lane] + part[128 + lane]
                      + bias[lane] + bias[64 + lane] + bias[128 + lane];
        hout[(size_t)n * 64 + lane] = v;
    }
}

// ---------------- layer 3: feat3 = h @ W3 (64->6) ----------------------------
__global__ void __launch_bounds__(256) k_feat3(const float* __restrict__ x,
                                               const float* __restrict__ W3,
                                               float* __restrict__ feat3) {
    __shared__ float Wl[64 * 6];
    __shared__ float xl[32 * 64];
    const int t = threadIdx.x;
    const int n0 = blockIdx.x * 32;
    const int nvalid = min(32, N_NODES - n0);
    for (int idx = t; idx < 384; idx += 256) Wl[idx] = W3[idx];
    for (int idx = t; idx < nvalid * 64; idx += 256) xl[idx] = x[(size_t)n0 * 64 + idx];
    __syncthreads();

    const int i = t >> 3;      // node within block
    const int slot = t & 7;    // 0..5 = output col, 6..7 idle
    if (i < nvalid && slot < 6) {
        float acc = 0.f;
#pragma unroll
        for (int k4 = 0; k4 < 16; ++k4) {
            const float4 xv = *reinterpret_cast<const float4*>(&xl[i * 64 + 4 * k4]);
            acc += Wl[(4 * k4 + 0) * 6 + slot] * xv.x;
            acc += Wl[(4 * k4 + 1) * 6 + slot] * xv.y;
            acc += Wl[(4 * k4 + 2) * 6 + slot] * xv.z;
            acc += Wl[(4 * k4 + 3) * 6 + slot] * xv.w;
        }
        feat3[(size_t)(n0 + i) * 8 + slot] = acc;
    }
}

// ---------------- layer-3 aggregation: 8 lanes/node, inline weights ----------
__global__ void __launch_bounds__(256) k_agg3(const float* __restrict__ feat3,
                                              const float* __restrict__ el3,
                                              const float* __restrict__ er3,
                                              const float* __restrict__ b3,
                                              const int* __restrict__ rowp,
                                              const int* __restrict__ col,
                                              float* __restrict__ out) {
    const int t = blockIdx.x * blockDim.x + threadIdx.x;
    const int n = t >> 3;
    const int r = t & 7;       // feature slot (0..5 valid; head = r/2)
    if (n >= N_NODES) return;
    int hh = r >> 1; if (hh > 2) hh = 2;
    const float ern = er3[(size_t)hh * N_NODES + n];
    const float* __restrict__ elh = el3 + (size_t)hh * N_NODES;
    const int jb = rowp[n], je = rowp[n + 1];
    float a = 0.f, sw = 0.f;
    for (int j = jb; j < je; ++j) {
        const int s = col[j];
        const float w = __expf(lrelu(elh[s] + ern));
        const float f = feat3[(size_t)s * 8 + r];
        a += w * f;
        sw += w;
    }
    float v = (je > jb && r < 6) ? (a / sw) : 0.f;
    v += __shfl_down(v, 2, 8);
    v += __shfl_down(v, 4, 8);
    if (r < 2) {
        const float bc = b3[r] + b3[r + 2] + b3[r + 4];
        out[(size_t)n * 2 + r] = v + bc;
    }
}

extern "C" void kernel_launch(void* const* d_in, const int* in_sizes, int n_in,
                              void* d_out, int out_size, void* d_ws, size_t ws_size,
                              hipStream_t stream) {
    const float* feats = (const float*)d_in[0];
    const int* src = (const int*)d_in[1];
    const int* dst = (const int*)d_in[2];
    const float* W1 = (const float*)d_in[3];
    const float* al1 = (const float*)d_in[4];
    const float* ar1 = (const float*)d_in[5];
    const float* b1 = (const float*)d_in[6];
    const float* W2 = (const float*)d_in[7];
    const float* al2 = (const float*)d_in[8];
    const float* ar2 = (const float*)d_in[9];
    const float* b2 = (const float*)d_in[10];
    const float* W3 = (const float*)d_in[11];
    const float* al3 = (const float*)d_in[12];
    const float* ar3 = (const float*)d_in[13];
    const float* b3 = (const float*)d_in[14];
    float* out = (float*)d_out;

    char* ws = (char*)d_ws;
    size_t off = 0;
    auto alloc = [&](size_t bytes) {
        void* p = ws + off;
        off += (bytes + 255) & ~(size_t)255;
        return p;
    };
    __half* featH = (__half*)alloc((size_t)3 * N_NODES * 64 * 2);  // 19.2 MB head-major
    float* hbuf = (float*)alloc((size_t)N_NODES * 64 * 4);         // 12.8 MB
    float* el = (float*)alloc((size_t)3 * N_NODES * 4);            // per-head planes
    float* er = (float*)alloc((size_t)3 * N_NODES * 4);
    int* deg = (int*)alloc((size_t)DEG_PAD * 4);                   // zero-padded
    int* fill = (int*)alloc((size_t)DEG_PAD * 4);
    int* rowp = (int*)alloc((size_t)(N_NODES + 1) * 4);
    int* col = (int*)alloc((size_t)N_EDGES * 4);
    int* bsum = (int*)alloc(64 * 4);
    int* boff = (int*)alloc(64 * 4);
    float* feat3 = (float*)alloc((size_t)N_NODES * 8 * 4);
    (void)ws_size;

    // ---- CSR build (deg & fill adjacent -> one memset) ----
    hipMemsetAsync(deg, 0, 2 * (size_t)DEG_PAD * 4, stream);
    int eb = (N_EDGES + 255) / 256;
    k_count<<<eb, 256, 0, stream>>>(dst, deg);
    k_scanA<<<NB_SCAN, 256, 0, stream>>>(deg, bsum);
    k_scanB<<<1, 64, 0, stream>>>(bsum, boff, rowp);
    k_scanC<<<NB_SCAN, 256, 0, stream>>>(deg, boff, rowp);
    k_scatter<<<eb, 256, 0, stream>>>(src, dst, rowp, fill, col);

    const int fb = 2500;                    // 2500 blocks x 5 groups x 4 = 50000
    const int nb = (N_NODES + 255) / 256;   // thread-per-node blocks
    const int nb3 = (N_NODES + 31) / 32;    // k_feat3: 32 nodes/block

    // ---- layer 1 ----
    k_el<9, 64><<<nb, 256, 0, stream>>>(feats, W1, al1, ar1, el, er);
    k_feat<9, 4, 5><<<fb, 192, 0, stream>>>(feats, W1, featH);
    k_agg<<<N_NODES, 192, 0, stream>>>(featH, el, er, b1, rowp, col, hbuf);

    // ---- layer 2 ----
    k_el<64, 64><<<nb, 256, 0, stream>>>(hbuf, W2, al2, ar2, el, er);
    k_feat<64, 4, 5><<<fb, 192, 0, stream>>>(hbuf, W2, featH);
    k_agg<<<N_NODES, 192, 0, stream>>>(featH, el, er, b2, rowp, col, hbuf);

    // ---- layer 3 ----
    k_el<64, 2><<<nb, 256, 0, stream>>>(hbuf, W3, al3, ar3, el, er);
    k_feat3<<<nb3, 256, 0, stream>>>(hbuf, W3, feat3);
    k_agg3<<<nb3, 256, 0, stream>>>(feat3, el, er, b3, rowp, col, out);
}

// Round 10
// 364.481 us; speedup vs baseline: 1.1899x; 1.1114x over previous
//
#include <hip/hip_runtime.h>
#include <hip/hip_fp16.h>

#define N_NODES 50000
#define N_EDGES 800000
#define NB_SCAN 49          // ceil(50000 / 1024)
#define DEG_PAD (NB_SCAN * 1024)   // 50176, zero-padded so int4 loads are unguarded

static __device__ __forceinline__ float lrelu(float x) { return fmaxf(x, 0.2f * x); }

// ---------------- CSR build ----------------
__global__ void k_count(const int* __restrict__ dst, int* __restrict__ deg) {
    int e = blockIdx.x * blockDim.x + threadIdx.x;
    if (e < N_EDGES) atomicAdd(&deg[dst[e]], 1);
}

__global__ void __launch_bounds__(256) k_scanA(const int* __restrict__ deg,
                                               int* __restrict__ bsum) {
    const int t = threadIdx.x;
    const int b = blockIdx.x;
    const int base = (b * 256 + t) * 4;
    const int4 v = *reinterpret_cast<const int4*>(deg + base);  // padded: safe
    int s = v.x + v.y + v.z + v.w;
#pragma unroll
    for (int off = 32; off > 0; off >>= 1) s += __shfl_down(s, off);
    __shared__ int ws[4];
    if ((t & 63) == 0) ws[t >> 6] = s;
    __syncthreads();
    if (t == 0) bsum[b] = ws[0] + ws[1] + ws[2] + ws[3];
}

__global__ void __launch_bounds__(64) k_scanB(const int* __restrict__ bsum,
                                              int* __restrict__ boff,
                                              int* __restrict__ rowp) {
    const int t = threadIdx.x;
    const int v = (t < NB_SCAN) ? bsum[t] : 0;
    int inc = v;
#pragma unroll
    for (int off = 1; off < 64; off <<= 1) {
        const int u = __shfl_up(inc, off);
        if (t >= off) inc += u;
    }
    if (t < NB_SCAN) boff[t] = inc - v;
    if (t == 0) rowp[N_NODES] = N_EDGES;
}

__global__ void __launch_bounds__(256) k_scanC(const int* __restrict__ deg,
                                               const int* __restrict__ boff,
                                               int* __restrict__ rowp) {
    const int t = threadIdx.x;
    const int b = blockIdx.x;
    const int lane = t & 63;
    const int wv = t >> 6;
    const int base = (b * 256 + t) * 4;
    const int4 v = *reinterpret_cast<const int4*>(deg + base);
    const int s = v.x + v.y + v.z + v.w;
    int inc = s;
#pragma unroll
    for (int off = 1; off < 64; off <<= 1) {
        const int u = __shfl_up(inc, off);
        if (lane >= off) inc += u;
    }
    __shared__ int wsum[4];
    if (lane == 63) wsum[wv] = inc;
    __syncthreads();
    int add = boff[b];
    for (int w = 0; w < wv; ++w) add += wsum[w];
    const int exc = add + inc - s;
    if (base < N_NODES) rowp[base] = exc;
    if (base + 1 < N_NODES) rowp[base + 1] = exc + v.x;
    if (base + 2 < N_NODES) rowp[base + 2] = exc + v.x + v.y;
    if (base + 3 < N_NODES) rowp[base + 3] = exc + v.x + v.y + v.z;
}

// scatter: single 4B write per edge (src only; dst implicit via CSR row)
__global__ void k_scatter(const int* __restrict__ src, const int* __restrict__ dst,
                          const int* __restrict__ rowp, int* __restrict__ fill,
                          int* __restrict__ col) {
    int e = blockIdx.x * blockDim.x + threadIdx.x;
    if (e < N_EDGES) {
        int d = dst[e];
        int pos = rowp[d] + atomicAdd(&fill[d], 1);
        col[pos] = src[e];
    }
}

// ---------------- el/er: el[n][h] = sum_k x[n,k]*Wa[k][h]; float4 [N][4] -----
template <int K, int F>
__global__ void __launch_bounds__(256) k_el(const float* __restrict__ x,
                                            const float* __restrict__ W,
                                            const float* __restrict__ al,
                                            const float* __restrict__ ar,
                                            float* __restrict__ el,
                                            float* __restrict__ er) {
    __shared__ float sWa[K * 3];
    __shared__ float sWr[K * 3];
    const int t = threadIdx.x;
    if (t < 3 * K) {
        const int h = t / K, k = t % K;
        float sa = 0.f, sr = 0.f;
        for (int f = 0; f < F; ++f) {
            const float w = W[k * 3 * F + h * F + f];
            sa += w * al[h * F + f];
            sr += w * ar[h * F + f];
        }
        sWa[k * 3 + h] = sa;
        sWr[k * 3 + h] = sr;
    }
    __syncthreads();
    const int n = blockIdx.x * 256 + t;
    if (n >= N_NODES) return;
    const float* __restrict__ xr = x + (size_t)n * K;
    float a0 = 0.f, a1 = 0.f, a2 = 0.f, r0 = 0.f, r1 = 0.f, r2 = 0.f;
#pragma unroll 4
    for (int k = 0; k < K; ++k) {
        const float xv = xr[k];
        a0 += xv * sWa[k * 3 + 0];
        a1 += xv * sWa[k * 3 + 1];
        a2 += xv * sWa[k * 3 + 2];
        r0 += xv * sWr[k * 3 + 0];
        r1 += xv * sWr[k * 3 + 1];
        r2 += xv * sWr[k * 3 + 2];
    }
    *reinterpret_cast<float4*>(el + (size_t)n * 4) = make_float4(a0, a1, a2, 0.f);
    *reinterpret_cast<float4*>(er + (size_t)n * 4) = make_float4(r0, r1, r2, 0.f);
}

// ---------------- feat = x @ W : pure GEMM, node-major fp16 [N][192] ---------
template <int K, int NPG, int GROUPS>
__global__ void __launch_bounds__(192) k_feat(const float* __restrict__ x,
                                              const float* __restrict__ W,
                                              __half* __restrict__ feat) {
    const int c = threadIdx.x;  // output column = h*64+f
    float wreg[K];
#pragma unroll
    for (int k = 0; k < K; ++k) wreg[k] = W[k * 192 + c];

    for (int g = 0; g < GROUPS; ++g) {
        const int nbase = (blockIdx.x * GROUPS + g) * NPG;  // grid sized exactly
        float acc[NPG];
#pragma unroll
        for (int i = 0; i < NPG; ++i) acc[i] = 0.f;
#pragma unroll
        for (int i = 0; i < NPG; ++i) {
            const int n = __builtin_amdgcn_readfirstlane(nbase + i);
            const float* __restrict__ xr = x + (size_t)n * K;
#pragma unroll
            for (int k = 0; k < K; ++k) acc[i] += xr[k] * wreg[k];
        }
#pragma unroll
        for (int i = 0; i < NPG; ++i)
            feat[(size_t)(nbase + i) * 192 + c] = __float2half(acc[i]);
    }
}

// ---------------- aggregation: wave/node; 1 dwordx2 gather covers 3 heads ----
// lane l<48: head h=l>>4, features (l&15)*4 .. +3 (8B of the 384B row).
// Per 64-edge chunk: phase1 computes per-lane edge weights (no redundant exp),
// phase2 gathers+accumulates with 4-edge unroll.
__global__ void __launch_bounds__(256) k_agg(const __half* __restrict__ feat,
                                             const float* __restrict__ el,
                                             const float* __restrict__ er,
                                             const float* __restrict__ bias,
                                             const int* __restrict__ rowp,
                                             const int* __restrict__ col,
                                             float* __restrict__ hout) {
    const int wv = threadIdx.x >> 6;
    const int lane = threadIdx.x & 63;
    const int n = blockIdx.x * 4 + wv;          // grid exact: 12500*4 = 50000
    const int jb = rowp[n], je = rowp[n + 1];

    __shared__ float wbuf[4][3][68];            // per-wave weights (+pad: no bank alias)
    __shared__ float comb[4][192];              // per-wave head-combine

    const float4 er4 = *reinterpret_cast<const float4*>(er + (size_t)n * 4);
    const int h = lane >> 4;                    // 0..2 active, 3 idle
    float acc0 = 0.f, acc1 = 0.f, acc2 = 0.f, acc3 = 0.f;
    float sw0 = 0.f, sw1 = 0.f, sw2 = 0.f;

    for (int c0 = jb; c0 < je; c0 += 64) {
        const int cnt = min(64, je - c0);
        // ---- phase 1: per-lane weights for this chunk ----
        float w0 = 0.f, w1 = 0.f, w2 = 0.f;
        if (lane < cnt) {
            const int s = col[c0 + lane];                       // coalesced
            const float4 e4 = *reinterpret_cast<const float4*>(el + (size_t)s * 4);
            w0 = __expf(lrelu(e4.x + er4.x));
            w1 = __expf(lrelu(e4.y + er4.y));
            w2 = __expf(lrelu(e4.z + er4.z));
            wbuf[wv][0][lane] = w0;
            wbuf[wv][1][lane] = w1;
            wbuf[wv][2][lane] = w2;
        }
        sw0 += w0; sw1 += w1; sw2 += w2;
        // ---- phase 2: gather + accumulate (lanes 0..47) ----
        if (lane < 48) {
            const float* __restrict__ wrow = &wbuf[wv][h][0];
            const __half* __restrict__ fl = feat + (size_t)lane * 4;
            int e = 0;
            for (; e + 4 <= cnt; e += 4) {
                const int sA = __builtin_amdgcn_readfirstlane(col[c0 + e + 0]);
                const int sB = __builtin_amdgcn_readfirstlane(col[c0 + e + 1]);
                const int sC = __builtin_amdgcn_readfirstlane(col[c0 + e + 2]);
                const int sD = __builtin_amdgcn_readfirstlane(col[c0 + e + 3]);
                const uint2 qA = *reinterpret_cast<const uint2*>(fl + (size_t)sA * 192);
                const uint2 qB = *reinterpret_cast<const uint2*>(fl + (size_t)sB * 192);
                const uint2 qC = *reinterpret_cast<const uint2*>(fl + (size_t)sC * 192);
                const uint2 qD = *reinterpret_cast<const uint2*>(fl + (size_t)sD * 192);
                const float wA = wrow[e + 0], wB = wrow[e + 1];
                const float wC = wrow[e + 2], wD = wrow[e + 3];
                {
                    const float2 a = __half22float2(*reinterpret_cast<const __half2*>(&qA.x));
                    const float2 b = __half22float2(*reinterpret_cast<const __half2*>(&qA.y));
                    acc0 += wA * a.x; acc1 += wA * a.y; acc2 += wA * b.x; acc3 += wA * b.y;
                }
                {
                    const float2 a = __half22float2(*reinterpret_cast<const __half2*>(&qB.x));
                    const float2 b = __half22float2(*reinterpret_cast<const __half2*>(&qB.y));
                    acc0 += wB * a.x; acc1 += wB * a.y; acc2 += wB * b.x; acc3 += wB * b.y;
                }
                {
                    const float2 a = __half22float2(*reinterpret_cast<const __half2*>(&qC.x));
                    const float2 b = __half22float2(*reinterpret_cast<const __half2*>(&qC.y));
                    acc0 += wC * a.x; acc1 += wC * a.y; acc2 += wC * b.x; acc3 += wC * b.y;
                }
                {
                    const float2 a = __half22float2(*reinterpret_cast<const __half2*>(&qD.x));
                    const float2 b = __half22float2(*reinterpret_cast<const __half2*>(&qD.y));
                    acc0 += wD * a.x; acc1 += wD * a.y; acc2 += wD * b.x; acc3 += wD * b.y;
                }
            }
            for (; e < cnt; ++e) {
                const int s = __builtin_amdgcn_readfirstlane(col[c0 + e]);
                const uint2 q = *reinterpret_cast<const uint2*>(fl + (size_t)s * 192);
                const float w = wrow[e];
                const float2 a = __half22float2(*reinterpret_cast<const __half2*>(&q.x));
                const float2 b = __half22float2(*reinterpret_cast<const __half2*>(&q.y));
                acc0 += w * a.x; acc1 += w * a.y; acc2 += w * b.x; acc3 += w * b.y;
            }
        }
    }

    // total softmax denominators (all 64 lanes participate)
#pragma unroll
    for (int off = 32; off > 0; off >>= 1) {
        sw0 += __shfl_xor(sw0, off);
        sw1 += __shfl_xor(sw1, off);
        sw2 += __shfl_xor(sw2, off);
    }

    if (lane < 48 && je > jb) {
        const float swh = (h == 0) ? sw0 : (h == 1 ? sw1 : sw2);
        const float inv = 1.f / swh;
        const int fbase = h * 64 + (lane & 15) * 4;
        comb[wv][fbase + 0] = acc0 * inv;
        comb[wv][fbase + 1] = acc1 * inv;
        comb[wv][fbase + 2] = acc2 * inv;
        comb[wv][fbase + 3] = acc3 * inv;
    }
    // same-wave LDS producer/consumer: in-order, compiler inserts lgkmcnt
    float r = bias[lane] + bias[64 + lane] + bias[128 + lane];
    if (je > jb) r += comb[wv][lane] + comb[wv][64 + lane] + comb[wv][128 + lane];
    hout[(size_t)n * 64 + lane] = r;
}

// ---------------- layer 3: feat3 = h @ W3 (64->6) ----------------------------
__global__ void __launch_bounds__(256) k_feat3(const float* __restrict__ x,
                                               const float* __restrict__ W3,
                                               float* __restrict__ feat3) {
    __shared__ float Wl[64 * 6];
    __shared__ float xl[32 * 64];
    const int t = threadIdx.x;
    const int n0 = blockIdx.x * 32;
    const int nvalid = min(32, N_NODES - n0);
    for (int idx = t; idx < 384; idx += 256) Wl[idx] = W3[idx];
    for (int idx = t; idx < nvalid * 64; idx += 256) xl[idx] = x[(size_t)n0 * 64 + idx];
    __syncthreads();

    const int i = t >> 3;
    const int slot = t & 7;
    if (i < nvalid && slot < 6) {
        float acc = 0.f;
#pragma unroll
        for (int k4 = 0; k4 < 16; ++k4) {
            const float4 xv = *reinterpret_cast<const float4*>(&xl[i * 64 + 4 * k4]);
            acc += Wl[(4 * k4 + 0) * 6 + slot] * xv.x;
            acc += Wl[(4 * k4 + 1) * 6 + slot] * xv.y;
            acc += Wl[(4 * k4 + 2) * 6 + slot] * xv.z;
            acc += Wl[(4 * k4 + 3) * 6 + slot] * xv.w;
        }
        feat3[(size_t)(n0 + i) * 8 + slot] = acc;
    }
}

// ---------------- layer-3 aggregation: 8 lanes/node, inline weights ----------
__global__ void __launch_bounds__(256) k_agg3(const float* __restrict__ feat3,
                                              const float* __restrict__ el3,
                                              const float* __restrict__ er3,
                                              const float* __restrict__ b3,
                                              const int* __restrict__ rowp,
                                              const int* __restrict__ col,
                                              float* __restrict__ out) {
    const int t = blockIdx.x * blockDim.x + threadIdx.x;
    const int n = t >> 3;
    const int r = t & 7;       // feature slot (0..5 valid; head = r/2)
    if (n >= N_NODES) return;
    int hh = r >> 1; if (hh > 2) hh = 2;
    const float ern = er3[(size_t)n * 4 + hh];
    const int jb = rowp[n], je = rowp[n + 1];
    float a = 0.f, sw = 0.f;
    for (int j = jb; j < je; ++j) {
        const int s = col[j];
        const float w = __expf(lrelu(el3[(size_t)s * 4 + hh] + ern));
        const float f = feat3[(size_t)s * 8 + r];
        a += w * f;
        sw += w;
    }
    float v = (je > jb && r < 6) ? (a / sw) : 0.f;
    v += __shfl_down(v, 2, 8);
    v += __shfl_down(v, 4, 8);
    if (r < 2) {
        const float bc = b3[r] + b3[r + 2] + b3[r + 4];
        out[(size_t)n * 2 + r] = v + bc;
    }
}

extern "C" void kernel_launch(void* const* d_in, const int* in_sizes, int n_in,
                              void* d_out, int out_size, void* d_ws, size_t ws_size,
                              hipStream_t stream) {
    const float* feats = (const float*)d_in[0];
    const int* src = (const int*)d_in[1];
    const int* dst = (const int*)d_in[2];
    const float* W1 = (const float*)d_in[3];
    const float* al1 = (const float*)d_in[4];
    const float* ar1 = (const float*)d_in[5];
    const float* b1 = (const float*)d_in[6];
    const float* W2 = (const float*)d_in[7];
    const float* al2 = (const float*)d_in[8];
    const float* ar2 = (const float*)d_in[9];
    const float* b2 = (const float*)d_in[10];
    const float* W3 = (const float*)d_in[11];
    const float* al3 = (const float*)d_in[12];
    const float* ar3 = (const float*)d_in[13];
    const float* b3 = (const float*)d_in[14];
    float* out = (float*)d_out;

    char* ws = (char*)d_ws;
    size_t off = 0;
    auto alloc = [&](size_t bytes) {
        void* p = ws + off;
        off += (bytes + 255) & ~(size_t)255;
        return p;
    };
    __half* featH = (__half*)alloc((size_t)N_NODES * 192 * 2 + 512);  // node-major [N][192]
    float* hbuf = (float*)alloc((size_t)N_NODES * 64 * 4);
    float* el = (float*)alloc((size_t)N_NODES * 4 * 4);
    float* er = (float*)alloc((size_t)N_NODES * 4 * 4);
    int* deg = (int*)alloc((size_t)DEG_PAD * 4);
    int* fill = (int*)alloc((size_t)DEG_PAD * 4);
    int* rowp = (int*)alloc((size_t)(N_NODES + 1) * 4);
    int* col = (int*)alloc((size_t)N_EDGES * 4);
    int* bsum = (int*)alloc(64 * 4);
    int* boff = (int*)alloc(64 * 4);
    float* feat3 = (float*)alloc((size_t)N_NODES * 8 * 4);
    (void)ws_size;

    // ---- CSR build (deg & fill adjacent -> one memset) ----
    hipMemsetAsync(deg, 0, 2 * (size_t)DEG_PAD * 4, stream);
    int eb = (N_EDGES + 255) / 256;
    k_count<<<eb, 256, 0, stream>>>(dst, deg);
    k_scanA<<<NB_SCAN, 256, 0, stream>>>(deg, bsum);
    k_scanB<<<1, 64, 0, stream>>>(bsum, boff, rowp);
    k_scanC<<<NB_SCAN, 256, 0, stream>>>(deg, boff, rowp);
    k_scatter<<<eb, 256, 0, stream>>>(src, dst, rowp, fill, col);

    const int fb = 2500;                    // k_feat: 2500 x 5 x 4 = 50000
    const int ab = N_NODES / 4;             // k_agg: 4 waves/block, wave/node
    const int nb = (N_NODES + 255) / 256;
    const int nb3 = (N_NODES + 31) / 32;

    // ---- layer 1 ----
    k_el<9, 64><<<nb, 256, 0, stream>>>(feats, W1, al1, ar1, el, er);
    k_feat<9, 4, 5><<<fb, 192, 0, stream>>>(feats, W1, featH);
    k_agg<<<ab, 256, 0, stream>>>(featH, el, er, b1, rowp, col, hbuf);

    // ---- layer 2 ----
    k_el<64, 64><<<nb, 256, 0, stream>>>(hbuf, W2, al2, ar2, el, er);
    k_feat<64, 4, 5><<<fb, 192, 0, stream>>>(hbuf, W2, featH);
    k_agg<<<ab, 256, 0, stream>>>(featH, el, er, b2, rowp, col, hbuf);

    // ---- layer 3 ----
    k_el<64, 2><<<nb, 256, 0, stream>>>(hbuf, W3, al3, ar3, el, er);
    k_feat3<<<nb3, 256, 0, stream>>>(hbuf, W3, feat3);
    k_agg3<<<nb3, 256, 0, stream>>>(feat3, el, er, b3, rowp, col, out);
}

// Round 11
// 342.367 us; speedup vs baseline: 1.2668x; 1.0646x over previous
//
#include <hip/hip_runtime.h>
#include <hip/hip_fp16.h>

#define N_NODES 50000
#define N_EDGES 800000
#define NB_SCAN 49          // ceil(50000 / 1024)
#define DEG_PAD (NB_SCAN * 1024)   // 50176, zero-padded so int4 loads are unguarded
#define NBKT 196            // ceil(50000 / 256) coarse buckets (dst >> 8)
#define EPB_BIN 4096        // edges per k_bin block
#define NB_BIN ((N_EDGES + EPB_BIN - 1) / EPB_BIN)   // 196

static __device__ __forceinline__ float lrelu(float x) { return fmaxf(x, 0.2f * x); }

// ---------------- CSR build ----------------
__global__ void k_count(const int* __restrict__ dst, int* __restrict__ deg) {
    int e = blockIdx.x * blockDim.x + threadIdx.x;
    if (e < N_EDGES) atomicAdd(&deg[dst[e]], 1);
}

__global__ void __launch_bounds__(256) k_scanA(const int* __restrict__ deg,
                                               int* __restrict__ bsum) {
    const int t = threadIdx.x;
    const int b = blockIdx.x;
    const int base = (b * 256 + t) * 4;
    const int4 v = *reinterpret_cast<const int4*>(deg + base);  // padded: safe
    int s = v.x + v.y + v.z + v.w;
#pragma unroll
    for (int off = 32; off > 0; off >>= 1) s += __shfl_down(s, off);
    __shared__ int ws[4];
    if ((t & 63) == 0) ws[t >> 6] = s;
    __syncthreads();
    if (t == 0) bsum[b] = ws[0] + ws[1] + ws[2] + ws[3];
}

__global__ void __launch_bounds__(64) k_scanB(const int* __restrict__ bsum,
                                              int* __restrict__ boff,
                                              int* __restrict__ rowp) {
    const int t = threadIdx.x;
    const int v = (t < NB_SCAN) ? bsum[t] : 0;
    int inc = v;
#pragma unroll
    for (int off = 1; off < 64; off <<= 1) {
        const int u = __shfl_up(inc, off);
        if (t >= off) inc += u;
    }
    if (t < NB_SCAN) boff[t] = inc - v;
    if (t == 0) rowp[N_NODES] = N_EDGES;
}

__global__ void __launch_bounds__(256) k_scanC(const int* __restrict__ deg,
                                               const int* __restrict__ boff,
                                               int* __restrict__ rowp) {
    const int t = threadIdx.x;
    const int b = blockIdx.x;
    const int lane = t & 63;
    const int wv = t >> 6;
    const int base = (b * 256 + t) * 4;
    const int4 v = *reinterpret_cast<const int4*>(deg + base);
    const int s = v.x + v.y + v.z + v.w;
    int inc = s;
#pragma unroll
    for (int off = 1; off < 64; off <<= 1) {
        const int u = __shfl_up(inc, off);
        if (lane >= off) inc += u;
    }
    __shared__ int wsum[4];
    if (lane == 63) wsum[wv] = inc;
    __syncthreads();
    int add = boff[b];
    for (int w = 0; w < wv; ++w) add += wsum[w];
    const int exc = add + inc - s;
    if (base < N_NODES) rowp[base] = exc;
    if (base + 1 < N_NODES) rowp[base + 1] = exc + v.x;
    if (base + 2 < N_NODES) rowp[base + 2] = exc + v.x + v.y;
    if (base + 3 < N_NODES) rowp[base + 3] = exc + v.x + v.y + v.z;
}

// ---------------- binned scatter, phase 1: edges -> bucket-contiguous stage --
// Bucket b = dst>>8 owns stage[rowp[b<<8] .. rowp[(b+1)<<8]). Each block
// reserves a private run per bucket (one global atomic per (block,bucket)),
// so stage lines are written by a single block -> no cross-XCD false sharing.
__global__ void __launch_bounds__(256) k_bin(const int* __restrict__ src,
                                             const int* __restrict__ dst,
                                             const int* __restrict__ rowp,
                                             int* __restrict__ bfill,
                                             int2* __restrict__ stage) {
    __shared__ int lcnt[NBKT];
    __shared__ int gb[NBKT];
    __shared__ int lf[NBKT];
    const int t = threadIdx.x;
    const int e0 = blockIdx.x * EPB_BIN;
    for (int i = t; i < NBKT; i += 256) lcnt[i] = 0;
    __syncthreads();
    int dcache[16];
#pragma unroll
    for (int i = 0; i < 16; ++i) {
        const int e = e0 + i * 256 + t;
        if (e < N_EDGES) {
            const int d = dst[e];
            dcache[i] = d;
            atomicAdd(&lcnt[d >> 8], 1);
        } else dcache[i] = -1;
    }
    __syncthreads();
    for (int i = t; i < NBKT; i += 256) {
        gb[i] = rowp[i << 8] + atomicAdd(&bfill[i], lcnt[i]);
        lf[i] = 0;
    }
    __syncthreads();
#pragma unroll
    for (int i = 0; i < 16; ++i) {
        const int e = e0 + i * 256 + t;
        if (e < N_EDGES) {
            const int d = dcache[i];
            const int b = d >> 8;
            const int r = atomicAdd(&lf[b], 1);
            stage[gb[b] + r] = make_int2(src[e], d);
        }
    }
}

// ---------------- binned scatter, phase 2: bucket -> final CSR col -----------
// One block per bucket; fill counters in LDS (bucket nodes are block-private);
// col writes land in a ~16KB window owned by this block.
__global__ void __launch_bounds__(256) k_bscatter(const int2* __restrict__ stage,
                                                  const int* __restrict__ rowp,
                                                  int* __restrict__ col) {
    __shared__ int srow[257];
    __shared__ int lf[256];
    const int t = threadIdx.x;
    const int n0 = blockIdx.x << 8;
    for (int i = t; i < 257; i += 256) srow[i] = rowp[min(n0 + i, N_NODES)];
    lf[t] = 0;
    __syncthreads();
    const int base = srow[0], end = srow[256];
    for (int j = base + t; j < end; j += 256) {
        const int2 e = stage[j];
        const int local = e.y - n0;
        const int pos = srow[local] + atomicAdd(&lf[local], 1);
        col[pos] = e.x;
    }
}

// ---------------- el/er: el[n][h] = sum_k x[n,k]*Wa[k][h]; float4 [N][4] -----
template <int K, int F>
__global__ void __launch_bounds__(256) k_el(const float* __restrict__ x,
                                            const float* __restrict__ W,
                                            const float* __restrict__ al,
                                            const float* __restrict__ ar,
                                            float* __restrict__ el,
                                            float* __restrict__ er) {
    __shared__ float sWa[K * 3];
    __shared__ float sWr[K * 3];
    const int t = threadIdx.x;
    if (t < 3 * K) {
        const int h = t / K, k = t % K;
        float sa = 0.f, sr = 0.f;
        for (int f = 0; f < F; ++f) {
            const float w = W[k * 3 * F + h * F + f];
            sa += w * al[h * F + f];
            sr += w * ar[h * F + f];
        }
        sWa[k * 3 + h] = sa;
        sWr[k * 3 + h] = sr;
    }
    __syncthreads();
    const int n = blockIdx.x * 256 + t;
    if (n >= N_NODES) return;
    const float* __restrict__ xr = x + (size_t)n * K;
    float a0 = 0.f, a1 = 0.f, a2 = 0.f, r0 = 0.f, r1 = 0.f, r2 = 0.f;
#pragma unroll 4
    for (int k = 0; k < K; ++k) {
        const float xv = xr[k];
        a0 += xv * sWa[k * 3 + 0];
        a1 += xv * sWa[k * 3 + 1];
        a2 += xv * sWa[k * 3 + 2];
        r0 += xv * sWr[k * 3 + 0];
        r1 += xv * sWr[k * 3 + 1];
        r2 += xv * sWr[k * 3 + 2];
    }
    *reinterpret_cast<float4*>(el + (size_t)n * 4) = make_float4(a0, a1, a2, 0.f);
    *reinterpret_cast<float4*>(er + (size_t)n * 4) = make_float4(r0, r1, r2, 0.f);
}

// ---------------- feat = x @ W : pure GEMM, node-major fp16 [N][192] ---------
template <int K, int NPG, int GROUPS>
__global__ void __launch_bounds__(192) k_feat(const float* __restrict__ x,
                                              const float* __restrict__ W,
                                              __half* __restrict__ feat) {
    const int c = threadIdx.x;  // output column = h*64+f
    float wreg[K];
#pragma unroll
    for (int k = 0; k < K; ++k) wreg[k] = W[k * 192 + c];

    for (int g = 0; g < GROUPS; ++g) {
        const int nbase = (blockIdx.x * GROUPS + g) * NPG;  // grid sized exactly
        float acc[NPG];
#pragma unroll
        for (int i = 0; i < NPG; ++i) acc[i] = 0.f;
#pragma unroll
        for (int i = 0; i < NPG; ++i) {
            const int n = __builtin_amdgcn_readfirstlane(nbase + i);
            const float* __restrict__ xr = x + (size_t)n * K;
#pragma unroll
            for (int k = 0; k < K; ++k) acc[i] += xr[k] * wreg[k];
        }
#pragma unroll
        for (int i = 0; i < NPG; ++i)
            feat[(size_t)(nbase + i) * 192 + c] = __float2half(acc[i]);
    }
}

// ---------------- aggregation: wave/node; 1 dwordx2 gather covers 3 heads ----
__global__ void __launch_bounds__(256) k_agg(const __half* __restrict__ feat,
                                             const float* __restrict__ el,
                                             const float* __restrict__ er,
                                             const float* __restrict__ bias,
                                             const int* __restrict__ rowp,
                                             const int* __restrict__ col,
                                             float* __restrict__ hout) {
    const int wv = threadIdx.x >> 6;
    const int lane = threadIdx.x & 63;
    const int n = blockIdx.x * 4 + wv;          // grid exact: 12500*4 = 50000
    const int jb = rowp[n], je = rowp[n + 1];

    __shared__ float wbuf[4][3][68];
    __shared__ float comb[4][192];

    const float4 er4 = *reinterpret_cast<const float4*>(er + (size_t)n * 4);
    const int h = lane >> 4;                    // 0..2 active, 3 idle
    float acc0 = 0.f, acc1 = 0.f, acc2 = 0.f, acc3 = 0.f;
    float sw0 = 0.f, sw1 = 0.f, sw2 = 0.f;

    for (int c0 = jb; c0 < je; c0 += 64) {
        const int cnt = min(64, je - c0);
        float w0 = 0.f, w1 = 0.f, w2 = 0.f;
        if (lane < cnt) {
            const int s = col[c0 + lane];                       // coalesced
            const float4 e4 = *reinterpret_cast<const float4*>(el + (size_t)s * 4);
            w0 = __expf(lrelu(e4.x + er4.x));
            w1 = __expf(lrelu(e4.y + er4.y));
            w2 = __expf(lrelu(e4.z + er4.z));
            wbuf[wv][0][lane] = w0;
            wbuf[wv][1][lane] = w1;
            wbuf[wv][2][lane] = w2;
        }
        sw0 += w0; sw1 += w1; sw2 += w2;
        if (lane < 48) {
            const float* __restrict__ wrow = &wbuf[wv][h][0];
            const __half* __restrict__ fl = feat + (size_t)lane * 4;
            int e = 0;
            for (; e + 4 <= cnt; e += 4) {
                const int sA = __builtin_amdgcn_readfirstlane(col[c0 + e + 0]);
                const int sB = __builtin_amdgcn_readfirstlane(col[c0 + e + 1]);
                const int sC = __builtin_amdgcn_readfirstlane(col[c0 + e + 2]);
                const int sD = __builtin_amdgcn_readfirstlane(col[c0 + e + 3]);
                const uint2 qA = *reinterpret_cast<const uint2*>(fl + (size_t)sA * 192);
                const uint2 qB = *reinterpret_cast<const uint2*>(fl + (size_t)sB * 192);
                const uint2 qC = *reinterpret_cast<const uint2*>(fl + (size_t)sC * 192);
                const uint2 qD = *reinterpret_cast<const uint2*>(fl + (size_t)sD * 192);
                const float wA = wrow[e + 0], wB = wrow[e + 1];
                const float wC = wrow[e + 2], wD = wrow[e + 3];
                {
                    const float2 a = __half22float2(*reinterpret_cast<const __half2*>(&qA.x));
                    const float2 b = __half22float2(*reinterpret_cast<const __half2*>(&qA.y));
                    acc0 += wA * a.x; acc1 += wA * a.y; acc2 += wA * b.x; acc3 += wA * b.y;
                }
                {
                    const float2 a = __half22float2(*reinterpret_cast<const __half2*>(&qB.x));
                    const float2 b = __half22float2(*reinterpret_cast<const __half2*>(&qB.y));
                    acc0 += wB * a.x; acc1 += wB * a.y; acc2 += wB * b.x; acc3 += wB * b.y;
                }
                {
                    const float2 a = __half22float2(*reinterpret_cast<const __half2*>(&qC.x));
                    const float2 b = __half22float2(*reinterpret_cast<const __half2*>(&qC.y));
                    acc0 += wC * a.x; acc1 += wC * a.y; acc2 += wC * b.x; acc3 += wC * b.y;
                }
                {
                    const float2 a = __half22float2(*reinterpret_cast<const __half2*>(&qD.x));
                    const float2 b = __half22float2(*reinterpret_cast<const __half2*>(&qD.y));
                    acc0 += wD * a.x; acc1 += wD * a.y; acc2 += wD * b.x; acc3 += wD * b.y;
                }
            }
            for (; e < cnt; ++e) {
                const int s = __builtin_amdgcn_readfirstlane(col[c0 + e]);
                const uint2 q = *reinterpret_cast<const uint2*>(fl + (size_t)s * 192);
                const float w = wrow[e];
                const float2 a = __half22float2(*reinterpret_cast<const __half2*>(&q.x));
                const float2 b = __half22float2(*reinterpret_cast<const __half2*>(&q.y));
                acc0 += w * a.x; acc1 += w * a.y; acc2 += w * b.x; acc3 += w * b.y;
            }
        }
    }

#pragma unroll
    for (int off = 32; off > 0; off >>= 1) {
        sw0 += __shfl_xor(sw0, off);
        sw1 += __shfl_xor(sw1, off);
        sw2 += __shfl_xor(sw2, off);
    }

    if (lane < 48 && je > jb) {
        const float swh = (h == 0) ? sw0 : (h == 1 ? sw1 : sw2);
        const float inv = 1.f / swh;
        const int fbase = h * 64 + (lane & 15) * 4;
        comb[wv][fbase + 0] = acc0 * inv;
        comb[wv][fbase + 1] = acc1 * inv;
        comb[wv][fbase + 2] = acc2 * inv;
        comb[wv][fbase + 3] = acc3 * inv;
    }
    float r = bias[lane] + bias[64 + lane] + bias[128 + lane];
    if (je > jb) r += comb[wv][lane] + comb[wv][64 + lane] + comb[wv][128 + lane];
    hout[(size_t)n * 64 + lane] = r;
}

// ---------------- layer 3: feat3 = h @ W3 (64->6) ----------------------------
__global__ void __launch_bounds__(256) k_feat3(const float* __restrict__ x,
                                               const float* __restrict__ W3,
                                               float* __restrict__ feat3) {
    __shared__ float Wl[64 * 6];
    __shared__ float xl[32 * 64];
    const int t = threadIdx.x;
    const int n0 = blockIdx.x * 32;
    const int nvalid = min(32, N_NODES - n0);
    for (int idx = t; idx < 384; idx += 256) Wl[idx] = W3[idx];
    for (int idx = t; idx < nvalid * 64; idx += 256) xl[idx] = x[(size_t)n0 * 64 + idx];
    __syncthreads();

    const int i = t >> 3;
    const int slot = t & 7;
    if (i < nvalid && slot < 6) {
        float acc = 0.f;
#pragma unroll
        for (int k4 = 0; k4 < 16; ++k4) {
            const float4 xv = *reinterpret_cast<const float4*>(&xl[i * 64 + 4 * k4]);
            acc += Wl[(4 * k4 + 0) * 6 + slot] * xv.x;
            acc += Wl[(4 * k4 + 1) * 6 + slot] * xv.y;
            acc += Wl[(4 * k4 + 2) * 6 + slot] * xv.z;
            acc += Wl[(4 * k4 + 3) * 6 + slot] * xv.w;
        }
        feat3[(size_t)(n0 + i) * 8 + slot] = acc;
    }
}

// ---------------- layer-3 aggregation: 8 lanes/node, inline weights ----------
__global__ void __launch_bounds__(256) k_agg3(const float* __restrict__ feat3,
                                              const float* __restrict__ el3,
                                              const float* __restrict__ er3,
                                              const float* __restrict__ b3,
                                              const int* __restrict__ rowp,
                                              const int* __restrict__ col,
                                              float* __restrict__ out) {
    const int t = blockIdx.x * blockDim.x + threadIdx.x;
    const int n = t >> 3;
    const int r = t & 7;       // feature slot (0..5 valid; head = r/2)
    if (n >= N_NODES) return;
    int hh = r >> 1; if (hh > 2) hh = 2;
    const float ern = er3[(size_t)n * 4 + hh];
    const int jb = rowp[n], je = rowp[n + 1];
    float a = 0.f, sw = 0.f;
    for (int j = jb; j < je; ++j) {
        const int s = col[j];
        const float w = __expf(lrelu(el3[(size_t)s * 4 + hh] + ern));
        const float f = feat3[(size_t)s * 8 + r];
        a += w * f;
        sw += w;
    }
    float v = (je > jb && r < 6) ? (a / sw) : 0.f;
    v += __shfl_down(v, 2, 8);
    v += __shfl_down(v, 4, 8);
    if (r < 2) {
        const float bc = b3[r] + b3[r + 2] + b3[r + 4];
        out[(size_t)n * 2 + r] = v + bc;
    }
}

extern "C" void kernel_launch(void* const* d_in, const int* in_sizes, int n_in,
                              void* d_out, int out_size, void* d_ws, size_t ws_size,
                              hipStream_t stream) {
    const float* feats = (const float*)d_in[0];
    const int* src = (const int*)d_in[1];
    const int* dst = (const int*)d_in[2];
    const float* W1 = (const float*)d_in[3];
    const float* al1 = (const float*)d_in[4];
    const float* ar1 = (const float*)d_in[5];
    const float* b1 = (const float*)d_in[6];
    const float* W2 = (const float*)d_in[7];
    const float* al2 = (const float*)d_in[8];
    const float* ar2 = (const float*)d_in[9];
    const float* b2 = (const float*)d_in[10];
    const float* W3 = (const float*)d_in[11];
    const float* al3 = (const float*)d_in[12];
    const float* ar3 = (const float*)d_in[13];
    const float* b3 = (const float*)d_in[14];
    float* out = (float*)d_out;

    char* ws = (char*)d_ws;
    size_t off = 0;
    auto alloc = [&](size_t bytes) {
        void* p = ws + off;
        off += (bytes + 255) & ~(size_t)255;
        return p;
    };
    __half* featH = (__half*)alloc((size_t)N_NODES * 192 * 2 + 512);  // node-major [N][192]
    float* hbuf = (float*)alloc((size_t)N_NODES * 64 * 4);
    float* el = (float*)alloc((size_t)N_NODES * 4 * 4);
    float* er = (float*)alloc((size_t)N_NODES * 4 * 4);
    int* deg = (int*)alloc(((size_t)DEG_PAD + 256) * 4);  // deg + bfill, one memset
    int* bfill = deg + DEG_PAD;
    int* rowp = (int*)alloc((size_t)(N_NODES + 1) * 4);
    int* col = (int*)alloc((size_t)N_EDGES * 4);
    int2* stage = (int2*)alloc((size_t)N_EDGES * 8);
    int* bsum = (int*)alloc(64 * 4);
    int* boff = (int*)alloc(64 * 4);
    float* feat3 = (float*)alloc((size_t)N_NODES * 8 * 4);
    (void)ws_size;

    // ---- CSR build ----
    hipMemsetAsync(deg, 0, ((size_t)DEG_PAD + 256) * 4, stream);
    int eb = (N_EDGES + 255) / 256;
    k_count<<<eb, 256, 0, stream>>>(dst, deg);
    k_scanA<<<NB_SCAN, 256, 0, stream>>>(deg, bsum);
    k_scanB<<<1, 64, 0, stream>>>(bsum, boff, rowp);
    k_scanC<<<NB_SCAN, 256, 0, stream>>>(deg, boff, rowp);
    k_bin<<<NB_BIN, 256, 0, stream>>>(src, dst, rowp, bfill, stage);
    k_bscatter<<<NBKT, 256, 0, stream>>>(stage, rowp, col);

    const int fb = 1250;                    // k_feat: 1250 x 5 x 8 = 50000
    const int ab = N_NODES / 4;             // k_agg: 4 waves/block, wave/node
    const int nb = (N_NODES + 255) / 256;
    const int nb3 = (N_NODES + 31) / 32;

    // ---- layer 1 ----
    k_el<9, 64><<<nb, 256, 0, stream>>>(feats, W1, al1, ar1, el, er);
    k_feat<9, 8, 5><<<fb, 192, 0, stream>>>(feats, W1, featH);
    k_agg<<<ab, 256, 0, stream>>>(featH, el, er, b1, rowp, col, hbuf);

    // ---- layer 2 ----
    k_el<64, 64><<<nb, 256, 0, stream>>>(hbuf, W2, al2, ar2, el, er);
    k_feat<64, 8, 5><<<fb, 192, 0, stream>>>(hbuf, W2, featH);
    k_agg<<<ab, 256, 0, stream>>>(featH, el, er, b2, rowp, col, hbuf);

    // ---- layer 3 ----
    k_el<64, 2><<<nb, 256, 0, stream>>>(hbuf, W3, al3, ar3, el, er);
    k_feat3<<<nb3, 256, 0, stream>>>(hbuf, W3, feat3);
    k_agg3<<<nb3, 256, 0, stream>>>(feat3, el, er, b3, rowp, col, out);
}